// Round 9
// baseline (351.849 us; speedup 1.0000x reference)
//
#include <hip/hip_runtime.h>
#include <hip/hip_fp16.h>

// ---------------------------------------------------------------------------
// GCN 3-layer forward, fused agg+GEMM layer.
//   g_l = dinv * h_l stored fp16 [N][128].  agg[dst] = sum_src g[src] + g[dst]
//   h_{l+1} = relu( dinv[dst]*(agg @ W) + b ); layers 1,2 store dinv*h, layer 3 h.
// Adjacency: two-pass binned ELL build (round-6 config).
// k_layer_f: 512 thr, 64 nodes/block. Phase 1: 16 half-waves gather 4 nodes
// each (8B/lane, 8-deep unroll -- the verified 3.6 TB/s structure) into an
// XOR-swizzled LDS tile. Phase 2: 8 waves MFMA 32x32x16 (D = Wt·agg^T),
// fused bias/relu/dinv epilogue. Saves the 51 MB/layer bufZ round-trip.
// ---------------------------------------------------------------------------

#define MAXDEG 64
#define NBUCKMAX 512
#define STAGE 32
#define BUCKCAP 8192

typedef _Float16 f16x8 __attribute__((ext_vector_type(8)));
typedef float f32x16 __attribute__((ext_vector_type(16)));

// ---- weights fp32->fp16 TRANSPOSED (Wt[f][k] = W[k][f]) + zero-inits -------
__global__ void k_cvtw(const float* __restrict__ W1, const float* __restrict__ W2,
                       const float* __restrict__ W3, __half* __restrict__ o1,
                       __half* __restrict__ o2, __half* __restrict__ o3,
                       float* __restrict__ pooled, float* __restrict__ gcnt,
                       int* __restrict__ gcur) {
    int i = blockIdx.x * blockDim.x + threadIdx.x;   // 16384, i = f*128+k
    int src = ((i & 127) << 7) + (i >> 7);           // W[k][f]
    o1[i] = __float2half_rn(W1[src]);
    o2[i] = __float2half_rn(W2[src]);
    o3[i] = __float2half_rn(W3[src]);
    pooled[i] = 0.f;
    if (i < 128) gcnt[i] = 0.f;
    if (i < NBUCKMAX) gcur[i] = 0;
}

// ---- pass A: bucket edges into per-bucket record regions -------------------
__global__ __launch_bounds__(256) void k_bucket(const int* __restrict__ row,
                                                const int* __restrict__ col,
                                                int E, int nbuck,
                                                int* __restrict__ gcur,
                                                int* __restrict__ recs) {
    __shared__ int stage[NBUCKMAX][STAGE];   // 64 KB
    __shared__ int scur[NBUCKMAX];
    int t = threadIdx.x;
    for (int i = t; i < NBUCKMAX; i += 256) scur[i] = 0;
    __syncthreads();

    int nblk = gridDim.x;
    int chunk = (((E + nblk - 1) / nblk) + 255) & ~255;
    int e0 = blockIdx.x * chunk;
    int e1 = e0 + chunk; if (e1 > E) e1 = E;

    for (int base = e0; base < e1; base += 256) {
        int e = base + t;
        if (e < e1) {
            int s = row[e], d = col[e];
            int b = d >> 8;
            int rec = (s << 8) | (d & 255);
            int slot = atomicAdd(&scur[b], 1);
            if (slot < STAGE) {
                stage[b][slot] = rec;
            } else {  // rare overflow: direct global
                int gp = atomicAdd(&gcur[b], 1);
                if (gp < BUCKCAP) recs[(size_t)b * BUCKCAP + gp] = rec;
            }
        }
        __syncthreads();
        for (int b = t; b < nbuck; b += 256) {
            int c = scur[b];
            if (c >= 24) {
                int n = c < STAGE ? c : STAGE;
                int gp = atomicAdd(&gcur[b], n);
                int* rg = recs + (size_t)b * BUCKCAP + gp;
                for (int k = 0; k < n; ++k) rg[k] = stage[b][k];
                scur[b] = 0;
            }
        }
        __syncthreads();
    }
    for (int b = t; b < nbuck; b += 256) {
        int c = scur[b];
        if (c > 0) {
            int n = c < STAGE ? c : STAGE;
            int gp = atomicAdd(&gcur[b], n);
            int* rg = recs + (size_t)b * BUCKCAP + gp;
            for (int k = 0; k < n; ++k) rg[k] = stage[b][k];
        }
    }
}

// ---- pass B: one block per bucket; build ELL slice (L2-resident) + cnt -----
__global__ __launch_bounds__(256) void k_build(const int* __restrict__ recs,
                                               const int* __restrict__ gcur,
                                               int* __restrict__ ell,
                                               int* __restrict__ cnt, int N) {
    __shared__ int lcnt[256];
    int b = blockIdx.x;
    int t = threadIdx.x;
    lcnt[t] = 0;
    __syncthreads();
    int n = gcur[b]; if (n > BUCKCAP) n = BUCKCAP;
    const int* rp = recs + (size_t)b * BUCKCAP;
    int base = b << 8;
    for (int i = t; i < n; i += 256) {
        int rec = rp[i];
        int dl = rec & 255;
        int s = rec >> 8;
        int r = atomicAdd(&lcnt[dl], 1);
        if (r < MAXDEG) ell[(size_t)(base + dl) * MAXDEG + r] = s;
    }
    __syncthreads();
    int node = base + t;
    if (node < N) cnt[node] = lcnt[t];
}

// ---- fused dinv + convert x -> g0 = dinv*x (fp16 [N][32] float2) -----------
__global__ __launch_bounds__(256) void k_prep(const float4* __restrict__ x,
                                              const int* __restrict__ cnt,
                                              float* __restrict__ dinv,
                                              float2* __restrict__ g0, int N) {
    int t = threadIdx.x;
    int slot = t >> 5, lane = t & 31;
    int node = blockIdx.x * 8 + slot;
    if (node >= N) return;
    float sc = rsqrtf((float)cnt[node] + 1.0f);
    if (lane == 0) dinv[node] = sc;
    float4 v = x[(size_t)node * 32 + lane];
    float2 o;
    ((__half2*)&o)[0] = __float22half2_rn(make_float2(v.x * sc, v.y * sc));
    ((__half2*)&o)[1] = __float22half2_rn(make_float2(v.z * sc, v.w * sc));
    g0[(size_t)node * 32 + lane] = o;
}

// ---- fused layer: gather-agg (16 half-waves x 4 nodes) -> LDS -> MFMA ------
__global__ __launch_bounds__(512) void k_layer_f(
    const float2* __restrict__ gin,  // [N][32] float2 (4 fp16 per lane)
    const int* __restrict__ ell,
    const int* __restrict__ cnt,
    const __half* __restrict__ Wt,   // [128 f][128 k] fp16 (= W^T)
    const float* __restrict__ bias,
    const float* __restrict__ dinv,
    __half* __restrict__ outp,       // [N][128] fp16
    int N, int scaleOut)
{
    __shared__ __align__(16) __half WtL[128 * 128];   // 32 KB, XOR-swizzled
    __shared__ __align__(16) __half tile[64 * 128];   // 16 KB, XOR-swizzled
    int t = threadIdx.x;
    int nb = blockIdx.x * 64;

    // stage Wt (swizzled): 2048 granules / 512 thr = 4 each
    const float4* Wg4 = (const float4*)Wt;
    float4* Wl4 = (float4*)WtL;
#pragma unroll
    for (int i = 0; i < 4; ++i) {
        int idx = t + i * 512;                 // granule idx, row = idx>>4
        int sidx = idx ^ ((idx >> 4) & 7);
        Wl4[sidx] = Wg4[idx];
    }

    // ---- phase 1: aggregate 4 nodes per half-wave into swizzled tile ------
    int slot = t >> 5;        // 0..15
    int lane = t & 31;
    float2* tl2 = (float2*)tile;
#pragma unroll
    for (int i = 0; i < 4; ++i) {
        int nl = slot + i * 16;               // 0..63 interleaved
        int node = nb + nl;
        float2 a0 = make_float2(0.f, 0.f), a1 = make_float2(0.f, 0.f);
        if (node < N) {
            float2 s = gin[(size_t)node * 32 + lane];
            a0 = __half22float2(((const __half2*)&s)[0]);   // self loop
            a1 = __half22float2(((const __half2*)&s)[1]);
            int deg = cnt[node]; if (deg > MAXDEG) deg = MAXDEG;
            const int* rowp = ell + (size_t)node * MAXDEG;
            int j = 0;
            for (; j + 7 < deg; j += 8) {
                int4 sa = *(const int4*)(rowp + j);
                int4 sb = *(const int4*)(rowp + j + 4);
                float2 v0 = gin[(size_t)sa.x * 32 + lane];
                float2 v1 = gin[(size_t)sa.y * 32 + lane];
                float2 v2 = gin[(size_t)sa.z * 32 + lane];
                float2 v3 = gin[(size_t)sa.w * 32 + lane];
                float2 v4 = gin[(size_t)sb.x * 32 + lane];
                float2 v5 = gin[(size_t)sb.y * 32 + lane];
                float2 v6 = gin[(size_t)sb.z * 32 + lane];
                float2 v7 = gin[(size_t)sb.w * 32 + lane];
                float2 f;
                f = __half22float2(((const __half2*)&v0)[0]); a0.x += f.x; a0.y += f.y;
                f = __half22float2(((const __half2*)&v0)[1]); a1.x += f.x; a1.y += f.y;
                f = __half22float2(((const __half2*)&v1)[0]); a0.x += f.x; a0.y += f.y;
                f = __half22float2(((const __half2*)&v1)[1]); a1.x += f.x; a1.y += f.y;
                f = __half22float2(((const __half2*)&v2)[0]); a0.x += f.x; a0.y += f.y;
                f = __half22float2(((const __half2*)&v2)[1]); a1.x += f.x; a1.y += f.y;
                f = __half22float2(((const __half2*)&v3)[0]); a0.x += f.x; a0.y += f.y;
                f = __half22float2(((const __half2*)&v3)[1]); a1.x += f.x; a1.y += f.y;
                f = __half22float2(((const __half2*)&v4)[0]); a0.x += f.x; a0.y += f.y;
                f = __half22float2(((const __half2*)&v4)[1]); a1.x += f.x; a1.y += f.y;
                f = __half22float2(((const __half2*)&v5)[0]); a0.x += f.x; a0.y += f.y;
                f = __half22float2(((const __half2*)&v5)[1]); a1.x += f.x; a1.y += f.y;
                f = __half22float2(((const __half2*)&v6)[0]); a0.x += f.x; a0.y += f.y;
                f = __half22float2(((const __half2*)&v6)[1]); a1.x += f.x; a1.y += f.y;
                f = __half22float2(((const __half2*)&v7)[0]); a0.x += f.x; a0.y += f.y;
                f = __half22float2(((const __half2*)&v7)[1]); a1.x += f.x; a1.y += f.y;
            }
            for (; j + 3 < deg; j += 4) {
                int4 s4 = *(const int4*)(rowp + j);
                float2 v0 = gin[(size_t)s4.x * 32 + lane];
                float2 v1 = gin[(size_t)s4.y * 32 + lane];
                float2 v2 = gin[(size_t)s4.z * 32 + lane];
                float2 v3 = gin[(size_t)s4.w * 32 + lane];
                float2 f;
                f = __half22float2(((const __half2*)&v0)[0]); a0.x += f.x; a0.y += f.y;
                f = __half22float2(((const __half2*)&v0)[1]); a1.x += f.x; a1.y += f.y;
                f = __half22float2(((const __half2*)&v1)[0]); a0.x += f.x; a0.y += f.y;
                f = __half22float2(((const __half2*)&v1)[1]); a1.x += f.x; a1.y += f.y;
                f = __half22float2(((const __half2*)&v2)[0]); a0.x += f.x; a0.y += f.y;
                f = __half22float2(((const __half2*)&v2)[1]); a1.x += f.x; a1.y += f.y;
                f = __half22float2(((const __half2*)&v3)[0]); a0.x += f.x; a0.y += f.y;
                f = __half22float2(((const __half2*)&v3)[1]); a1.x += f.x; a1.y += f.y;
            }
            for (; j < deg; ++j) {
                int s0 = rowp[j];
                float2 v0 = gin[(size_t)s0 * 32 + lane];
                float2 f;
                f = __half22float2(((const __half2*)&v0)[0]); a0.x += f.x; a0.y += f.y;
                f = __half22float2(((const __half2*)&v0)[1]); a1.x += f.x; a1.y += f.y;
            }
        }
        float2 o;
        ((__half2*)&o)[0] = __float22half2_rn(a0);
        ((__half2*)&o)[1] = __float22half2_rn(a1);
        int g = nl * 16 + (lane >> 1);          // 16B granule, row = g>>4 = nl
        int gs = g ^ ((g >> 4) & 7);
        tl2[gs * 2 + (lane & 1)] = o;
    }
    __syncthreads();

    // ---- phase 2: MFMA. 8 waves: subtile s = wave>>2 (32 nodes), ft = wave&3
    int wave = t >> 6, l64 = t & 63;
    int ln31 = l64 & 31;
    int khalf = l64 >> 5;                      // 0/1
    int s = wave >> 2, ft = wave & 3;
    int nl = s * 32 + ln31;
    int node = nb + nl;
    bool valid = node < N;
    const float4* tl4 = (const float4*)tile;

    f32x16 acc = {0.f, 0.f, 0.f, 0.f, 0.f, 0.f, 0.f, 0.f,
                  0.f, 0.f, 0.f, 0.f, 0.f, 0.f, 0.f, 0.f};
#pragma unroll
    for (int kc = 0; kc < 8; ++kc) {
        int aidx = (ft * 32 + ln31) * 16 + kc * 2 + khalf;
        int as = aidx ^ ((aidx >> 4) & 7);
        f16x8 afrag = *(const f16x8*)&Wl4[as];
        int bidx = nl * 16 + kc * 2 + khalf;
        int bs = bidx ^ ((bidx >> 4) & 7);
        f16x8 bfrag = *(const f16x8*)&tl4[bs];
        acc = __builtin_amdgcn_mfma_f32_32x32x16_f16(afrag, bfrag, acc, 0, 0, 0);
    }
    if (valid) {
        float scn = dinv[node];
        size_t nrow = (size_t)node * 128;
#pragma unroll
        for (int q = 0; q < 4; ++q) {
            int f = ft * 32 + q * 8 + khalf * 4;
            float4 bb = *(const float4*)&bias[f];
            float o0 = fmaxf(acc[q * 4 + 0] * scn + bb.x, 0.f);
            float o1 = fmaxf(acc[q * 4 + 1] * scn + bb.y, 0.f);
            float o2 = fmaxf(acc[q * 4 + 2] * scn + bb.z, 0.f);
            float o3 = fmaxf(acc[q * 4 + 3] * scn + bb.w, 0.f);
            if (scaleOut) { o0 *= scn; o1 *= scn; o2 *= scn; o3 *= scn; }
            float2 st;
            ((__half2*)&st)[0] = __float22half2_rn(make_float2(o0, o1));
            ((__half2*)&st)[1] = __float22half2_rn(make_float2(o2, o3));
            *(float2*)&outp[nrow + f] = st;
        }
    }
}

// ---- mean-pool per graph (batch sorted): run-length partial sums -----------
__global__ __launch_bounds__(128) void k_pool(const __half* __restrict__ h,
                                              const int* __restrict__ batch,
                                              float* __restrict__ pooled,
                                              float* __restrict__ gcnt, int N) {
    int t = threadIdx.x;
    int base = blockIdx.x * 128;
    if (base >= N) return;
    int end = base + 128; if (end > N) end = N;
    int g = batch[base];
    float acc = 0.f;
    int run = 0;
    for (int n = base; n < end; ++n) {
        int bg = batch[n];
        if (bg != g) {
            atomicAdd(&pooled[g * 128 + t], acc);
            if (t == 0) atomicAdd(&gcnt[g], (float)run);
            acc = 0.f; run = 0; g = bg;
        }
        acc += __half2float(h[(size_t)n * 128 + t]);
        run++;
    }
    atomicAdd(&pooled[g * 128 + t], acc);
    if (t == 0) atomicAdd(&gcnt[g], (float)run);
}

// ---- FFN: out[g] = relu(pooled_mean @ Wf1 + bf1) @ Wf2 + bf2 ---------------
__global__ __launch_bounds__(128) void k_ffn(const float* __restrict__ pooled,
                                             const float* __restrict__ gcnt,
                                             const float* __restrict__ Wf1,
                                             const float* __restrict__ bf1,
                                             const float* __restrict__ Wf2,
                                             const float* __restrict__ bf2,
                                             float* __restrict__ out, int C) {
    __shared__ float pl[128];
    __shared__ float hid[128];
    int g = blockIdx.x;
    int t = threadIdx.x;
    float invc = 1.0f / fmaxf(gcnt[g], 1.0f);
    pl[t] = pooled[g * 128 + t] * invc;
    __syncthreads();
    float s = bf1[t];
    for (int k = 0; k < 128; ++k) s += pl[k] * Wf1[k * 128 + t];
    hid[t] = fmaxf(s, 0.f);
    __syncthreads();
    if (t < C) {
        float o = bf2[t];
        for (int f = 0; f < 128; ++f) o += hid[f] * Wf2[f * C + t];
        out[g * C + t] = o;
    }
}

extern "C" void kernel_launch(void* const* d_in, const int* in_sizes, int n_in,
                              void* d_out, int out_size, void* d_ws, size_t ws_size,
                              hipStream_t stream) {
    const float* x   = (const float*)d_in[0];
    const int*   ei  = (const int*)d_in[1];
    const int*   bat = (const int*)d_in[2];
    const float* W1  = (const float*)d_in[3];
    const float* b1  = (const float*)d_in[4];
    const float* W2  = (const float*)d_in[5];
    const float* b2  = (const float*)d_in[6];
    const float* W3  = (const float*)d_in[7];
    const float* b3  = (const float*)d_in[8];
    const float* Wf1 = (const float*)d_in[9];
    const float* bf1 = (const float*)d_in[10];
    const float* Wf2 = (const float*)d_in[11];
    const float* bf2 = (const float*)d_in[12];
    float* out = (float*)d_out;

    int N = in_sizes[2];
    int E = in_sizes[1] / 2;
    int C = in_sizes[12];
    const int* row  = ei;
    const int* colv = ei + E;

    int nbuck = (N + 255) / 256;
    int Npad  = nbuck * 256;

    auto align256 = [](char* p) {
        return (char*)(((uintptr_t)p + 255) & ~(uintptr_t)255);
    };
    char* w = (char*)d_ws;
    __half* bufX = (__half*)w; w += (size_t)N * 128 * 2; w = align256(w);
    __half* bufY = (__half*)w; w += (size_t)N * 128 * 2; w = align256(w);
    int* ell     = (int*)w;   w += (size_t)Npad * MAXDEG * 4; w = align256(w);
    int* recs    = (int*)w;   w += (size_t)nbuck * BUCKCAP * 4; w = align256(w);
    int* cnt     = (int*)w;   w += (size_t)Npad * 4;    w = align256(w);
    float* dinv  = (float*)w; w += (size_t)N * 4;       w = align256(w);
    int* gcur    = (int*)w;   w += NBUCKMAX * 4;        w = align256(w);
    __half* Wt1  = (__half*)w; w += 128 * 128 * 2;      w = align256(w);
    __half* Wt2  = (__half*)w; w += 128 * 128 * 2;      w = align256(w);
    __half* Wt3  = (__half*)w; w += 128 * 128 * 2;      w = align256(w);
    float* pooled= (float*)w;  w += 128 * 128 * 4;      w = align256(w);
    float* gcnt  = (float*)w;  w += 128 * 4;

    int nnode8 = (N + 7) / 8;
    int nlayer = (N + 63) / 64;

    k_cvtw  <<<64, 256, 0, stream>>>(W1, W2, W3, Wt1, Wt2, Wt3, pooled, gcnt, gcur);
    k_bucket<<<256, 256, 0, stream>>>(row, colv, E, nbuck, gcur, recs);
    k_build <<<nbuck, 256, 0, stream>>>(recs, gcur, ell, cnt, N);
    k_prep  <<<nnode8, 256, 0, stream>>>((const float4*)x, cnt, dinv,
                                         (float2*)bufX, N);

    // layer 1: bufX -> bufY (scaled)
    k_layer_f<<<nlayer, 512, 0, stream>>>((const float2*)bufX, ell, cnt,
                                          Wt1, b1, dinv, bufY, N, 1);
    // layer 2: bufY -> bufX (scaled)
    k_layer_f<<<nlayer, 512, 0, stream>>>((const float2*)bufY, ell, cnt,
                                          Wt2, b2, dinv, bufX, N, 1);
    // layer 3: bufX -> bufY (unscaled, for pooling)
    k_layer_f<<<nlayer, 512, 0, stream>>>((const float2*)bufX, ell, cnt,
                                          Wt3, b3, dinv, bufY, N, 0);

    k_pool<<<(N + 127) / 128, 128, 0, stream>>>(bufY, bat, pooled, gcnt, N);
    k_ffn <<<128, 128, 0, stream>>>(pooled, gcnt, Wf1, bf1, Wf2, bf2, out, C);
}

// Round 10
// 348.488 us; speedup vs baseline: 1.0096x; 1.0096x over previous
//
#include <hip/hip_runtime.h>
#include <hip/hip_fp16.h>

// ---------------------------------------------------------------------------
// GCN 3-layer forward, fused agg+GEMM layer (v2: no Wt LDS staging).
//   g_l = dinv * h_l stored fp16 [N][128].  agg[dst] = sum_src g[src] + g[dst]
//   h_{l+1} = relu( dinv[dst]*(agg @ W) + b ); layers 1,2 store dinv*h, layer 3 h.
// Adjacency: two-pass binned ELL build (round-6 config).
// k_layer_f: 512 thr, 64 nodes/block, LDS = 16KB tile only -> 4 blocks/CU.
//   Phase 1: 16 half-waves gather 4 nodes each (8B/lane, 8-deep unroll) into
//   XOR-swizzled LDS tile. Phase 2: 8 waves MFMA 32x32x16, A-fragments read
//   DIRECTLY FROM GLOBAL Wt (32KB, L1-resident), fused bias/relu/dinv epilogue.
// ---------------------------------------------------------------------------

#define MAXDEG 64
#define NBUCKMAX 512
#define STAGE 32
#define BUCKCAP 8192

typedef _Float16 f16x8 __attribute__((ext_vector_type(8)));
typedef float f32x16 __attribute__((ext_vector_type(16)));

// ---- weights fp32->fp16 TRANSPOSED (Wt[f][k] = W[k][f]) + zero-inits -------
__global__ void k_cvtw(const float* __restrict__ W1, const float* __restrict__ W2,
                       const float* __restrict__ W3, __half* __restrict__ o1,
                       __half* __restrict__ o2, __half* __restrict__ o3,
                       float* __restrict__ pooled, float* __restrict__ gcnt,
                       int* __restrict__ gcur) {
    int i = blockIdx.x * blockDim.x + threadIdx.x;   // 16384, i = f*128+k
    int src = ((i & 127) << 7) + (i >> 7);           // W[k][f]
    o1[i] = __float2half_rn(W1[src]);
    o2[i] = __float2half_rn(W2[src]);
    o3[i] = __float2half_rn(W3[src]);
    pooled[i] = 0.f;
    if (i < 128) gcnt[i] = 0.f;
    if (i < NBUCKMAX) gcur[i] = 0;
}

// ---- pass A: bucket edges into per-bucket record regions -------------------
__global__ __launch_bounds__(256) void k_bucket(const int* __restrict__ row,
                                                const int* __restrict__ col,
                                                int E, int nbuck,
                                                int* __restrict__ gcur,
                                                int* __restrict__ recs) {
    __shared__ int stage[NBUCKMAX][STAGE];   // 64 KB
    __shared__ int scur[NBUCKMAX];
    int t = threadIdx.x;
    for (int i = t; i < NBUCKMAX; i += 256) scur[i] = 0;
    __syncthreads();

    int nblk = gridDim.x;
    int chunk = (((E + nblk - 1) / nblk) + 255) & ~255;
    int e0 = blockIdx.x * chunk;
    int e1 = e0 + chunk; if (e1 > E) e1 = E;

    for (int base = e0; base < e1; base += 256) {
        int e = base + t;
        if (e < e1) {
            int s = row[e], d = col[e];
            int b = d >> 8;
            int rec = (s << 8) | (d & 255);
            int slot = atomicAdd(&scur[b], 1);
            if (slot < STAGE) {
                stage[b][slot] = rec;
            } else {  // rare overflow: direct global
                int gp = atomicAdd(&gcur[b], 1);
                if (gp < BUCKCAP) recs[(size_t)b * BUCKCAP + gp] = rec;
            }
        }
        __syncthreads();
        for (int b = t; b < nbuck; b += 256) {
            int c = scur[b];
            if (c >= 24) {
                int n = c < STAGE ? c : STAGE;
                int gp = atomicAdd(&gcur[b], n);
                int* rg = recs + (size_t)b * BUCKCAP + gp;
                for (int k = 0; k < n; ++k) rg[k] = stage[b][k];
                scur[b] = 0;
            }
        }
        __syncthreads();
    }
    for (int b = t; b < nbuck; b += 256) {
        int c = scur[b];
        if (c > 0) {
            int n = c < STAGE ? c : STAGE;
            int gp = atomicAdd(&gcur[b], n);
            int* rg = recs + (size_t)b * BUCKCAP + gp;
            for (int k = 0; k < n; ++k) rg[k] = stage[b][k];
        }
    }
}

// ---- pass B: one block per bucket; build ELL slice (L2-resident) + cnt -----
__global__ __launch_bounds__(256) void k_build(const int* __restrict__ recs,
                                               const int* __restrict__ gcur,
                                               int* __restrict__ ell,
                                               int* __restrict__ cnt, int N) {
    __shared__ int lcnt[256];
    int b = blockIdx.x;
    int t = threadIdx.x;
    lcnt[t] = 0;
    __syncthreads();
    int n = gcur[b]; if (n > BUCKCAP) n = BUCKCAP;
    const int* rp = recs + (size_t)b * BUCKCAP;
    int base = b << 8;
    for (int i = t; i < n; i += 256) {
        int rec = rp[i];
        int dl = rec & 255;
        int s = rec >> 8;
        int r = atomicAdd(&lcnt[dl], 1);
        if (r < MAXDEG) ell[(size_t)(base + dl) * MAXDEG + r] = s;
    }
    __syncthreads();
    int node = base + t;
    if (node < N) cnt[node] = lcnt[t];
}

// ---- fused dinv + convert x -> g0 = dinv*x (fp16 [N][32] float2) -----------
__global__ __launch_bounds__(256) void k_prep(const float4* __restrict__ x,
                                              const int* __restrict__ cnt,
                                              float* __restrict__ dinv,
                                              float2* __restrict__ g0, int N) {
    int t = threadIdx.x;
    int slot = t >> 5, lane = t & 31;
    int node = blockIdx.x * 8 + slot;
    if (node >= N) return;
    float sc = rsqrtf((float)cnt[node] + 1.0f);
    if (lane == 0) dinv[node] = sc;
    float4 v = x[(size_t)node * 32 + lane];
    float2 o;
    ((__half2*)&o)[0] = __float22half2_rn(make_float2(v.x * sc, v.y * sc));
    ((__half2*)&o)[1] = __float22half2_rn(make_float2(v.z * sc, v.w * sc));
    g0[(size_t)node * 32 + lane] = o;
}

// ---- fused layer: gather-agg -> 16KB LDS tile -> MFMA (Wt from global) -----
__global__ __launch_bounds__(512, 8) void k_layer_f(
    const float2* __restrict__ gin,  // [N][32] float2 (4 fp16 per lane)
    const int* __restrict__ ell,
    const int* __restrict__ cnt,
    const __half* __restrict__ Wt,   // [128 f][128 k] fp16 (= W^T), L1-resident
    const float* __restrict__ bias,
    const float* __restrict__ dinv,
    __half* __restrict__ outp,       // [N][128] fp16
    int N, int scaleOut)
{
    __shared__ __align__(16) __half tile[64 * 128];   // 16 KB, XOR-swizzled
    int t = threadIdx.x;
    int nb = blockIdx.x * 64;

    // ---- phase 1: aggregate 4 nodes per half-wave into swizzled tile ------
    int slot = t >> 5;        // 0..15
    int lane = t & 31;
    float2* tl2 = (float2*)tile;
#pragma unroll
    for (int i = 0; i < 4; ++i) {
        int nl = slot + i * 16;               // 0..63 interleaved
        int node = nb + nl;
        float2 a0 = make_float2(0.f, 0.f), a1 = make_float2(0.f, 0.f);
        if (node < N) {
            float2 s = gin[(size_t)node * 32 + lane];
            a0 = __half22float2(((const __half2*)&s)[0]);   // self loop
            a1 = __half22float2(((const __half2*)&s)[1]);
            int deg = cnt[node]; if (deg > MAXDEG) deg = MAXDEG;
            const int* rowp = ell + (size_t)node * MAXDEG;
            int j = 0;
            for (; j + 7 < deg; j += 8) {
                int4 sa = *(const int4*)(rowp + j);
                int4 sb = *(const int4*)(rowp + j + 4);
                float2 v0 = gin[(size_t)sa.x * 32 + lane];
                float2 v1 = gin[(size_t)sa.y * 32 + lane];
                float2 v2 = gin[(size_t)sa.z * 32 + lane];
                float2 v3 = gin[(size_t)sa.w * 32 + lane];
                float2 v4 = gin[(size_t)sb.x * 32 + lane];
                float2 v5 = gin[(size_t)sb.y * 32 + lane];
                float2 v6 = gin[(size_t)sb.z * 32 + lane];
                float2 v7 = gin[(size_t)sb.w * 32 + lane];
                float2 f;
                f = __half22float2(((const __half2*)&v0)[0]); a0.x += f.x; a0.y += f.y;
                f = __half22float2(((const __half2*)&v0)[1]); a1.x += f.x; a1.y += f.y;
                f = __half22float2(((const __half2*)&v1)[0]); a0.x += f.x; a0.y += f.y;
                f = __half22float2(((const __half2*)&v1)[1]); a1.x += f.x; a1.y += f.y;
                f = __half22float2(((const __half2*)&v2)[0]); a0.x += f.x; a0.y += f.y;
                f = __half22float2(((const __half2*)&v2)[1]); a1.x += f.x; a1.y += f.y;
                f = __half22float2(((const __half2*)&v3)[0]); a0.x += f.x; a0.y += f.y;
                f = __half22float2(((const __half2*)&v3)[1]); a1.x += f.x; a1.y += f.y;
                f = __half22float2(((const __half2*)&v4)[0]); a0.x += f.x; a0.y += f.y;
                f = __half22float2(((const __half2*)&v4)[1]); a1.x += f.x; a1.y += f.y;
                f = __half22float2(((const __half2*)&v5)[0]); a0.x += f.x; a0.y += f.y;
                f = __half22float2(((const __half2*)&v5)[1]); a1.x += f.x; a1.y += f.y;
                f = __half22float2(((const __half2*)&v6)[0]); a0.x += f.x; a0.y += f.y;
                f = __half22float2(((const __half2*)&v6)[1]); a1.x += f.x; a1.y += f.y;
                f = __half22float2(((const __half2*)&v7)[0]); a0.x += f.x; a0.y += f.y;
                f = __half22float2(((const __half2*)&v7)[1]); a1.x += f.x; a1.y += f.y;
            }
            for (; j + 3 < deg; j += 4) {
                int4 s4 = *(const int4*)(rowp + j);
                float2 v0 = gin[(size_t)s4.x * 32 + lane];
                float2 v1 = gin[(size_t)s4.y * 32 + lane];
                float2 v2 = gin[(size_t)s4.z * 32 + lane];
                float2 v3 = gin[(size_t)s4.w * 32 + lane];
                float2 f;
                f = __half22float2(((const __half2*)&v0)[0]); a0.x += f.x; a0.y += f.y;
                f = __half22float2(((const __half2*)&v0)[1]); a1.x += f.x; a1.y += f.y;
                f = __half22float2(((const __half2*)&v1)[0]); a0.x += f.x; a0.y += f.y;
                f = __half22float2(((const __half2*)&v1)[1]); a1.x += f.x; a1.y += f.y;
                f = __half22float2(((const __half2*)&v2)[0]); a0.x += f.x; a0.y += f.y;
                f = __half22float2(((const __half2*)&v2)[1]); a1.x += f.x; a1.y += f.y;
                f = __half22float2(((const __half2*)&v3)[0]); a0.x += f.x; a0.y += f.y;
                f = __half22float2(((const __half2*)&v3)[1]); a1.x += f.x; a1.y += f.y;
            }
            for (; j < deg; ++j) {
                int s0 = rowp[j];
                float2 v0 = gin[(size_t)s0 * 32 + lane];
                float2 f;
                f = __half22float2(((const __half2*)&v0)[0]); a0.x += f.x; a0.y += f.y;
                f = __half22float2(((const __half2*)&v0)[1]); a1.x += f.x; a1.y += f.y;
            }
        }
        float2 o;
        ((__half2*)&o)[0] = __float22half2_rn(a0);
        ((__half2*)&o)[1] = __float22half2_rn(a1);
        int g = nl * 16 + (lane >> 1);          // 16B granule, row = g>>4 = nl
        int gs = g ^ ((g >> 4) & 7);
        tl2[gs * 2 + (lane & 1)] = o;
    }
    __syncthreads();

    // ---- phase 2: MFMA. 8 waves: subtile s = wave>>2 (32 nodes), ft = wave&3
    int wave = t >> 6, l64 = t & 63;
    int ln31 = l64 & 31;
    int khalf = l64 >> 5;                      // 0/1
    int s = wave >> 2, ft = wave & 3;
    int nl = s * 32 + ln31;
    int node = nb + nl;
    bool valid = node < N;
    const float4* tl4 = (const float4*)tile;
    const float4* Wg4 = (const float4*)Wt;     // global, L1-hot

    f32x16 acc = {0.f, 0.f, 0.f, 0.f, 0.f, 0.f, 0.f, 0.f,
                  0.f, 0.f, 0.f, 0.f, 0.f, 0.f, 0.f, 0.f};
#pragma unroll
    for (int kc = 0; kc < 8; ++kc) {
        int aidx = (ft * 32 + ln31) * 16 + kc * 2 + khalf;
        f16x8 afrag = *(const f16x8*)&Wg4[aidx];
        int bidx = nl * 16 + kc * 2 + khalf;
        int bs = bidx ^ ((bidx >> 4) & 7);
        f16x8 bfrag = *(const f16x8*)&tl4[bs];
        acc = __builtin_amdgcn_mfma_f32_32x32x16_f16(afrag, bfrag, acc, 0, 0, 0);
    }
    if (valid) {
        float scn = dinv[node];
        size_t nrow = (size_t)node * 128;
#pragma unroll
        for (int q = 0; q < 4; ++q) {
            int f = ft * 32 + q * 8 + khalf * 4;
            float4 bb = *(const float4*)&bias[f];
            float o0 = fmaxf(acc[q * 4 + 0] * scn + bb.x, 0.f);
            float o1 = fmaxf(acc[q * 4 + 1] * scn + bb.y, 0.f);
            float o2 = fmaxf(acc[q * 4 + 2] * scn + bb.z, 0.f);
            float o3 = fmaxf(acc[q * 4 + 3] * scn + bb.w, 0.f);
            if (scaleOut) { o0 *= scn; o1 *= scn; o2 *= scn; o3 *= scn; }
            float2 st;
            ((__half2*)&st)[0] = __float22half2_rn(make_float2(o0, o1));
            ((__half2*)&st)[1] = __float22half2_rn(make_float2(o2, o3));
            *(float2*)&outp[nrow + f] = st;
        }
    }
}

// ---- mean-pool per graph (batch sorted): run-length partial sums -----------
__global__ __launch_bounds__(128) void k_pool(const __half* __restrict__ h,
                                              const int* __restrict__ batch,
                                              float* __restrict__ pooled,
                                              float* __restrict__ gcnt, int N) {
    int t = threadIdx.x;
    int base = blockIdx.x * 128;
    if (base >= N) return;
    int end = base + 128; if (end > N) end = N;
    int g = batch[base];
    float acc = 0.f;
    int run = 0;
    for (int n = base; n < end; ++n) {
        int bg = batch[n];
        if (bg != g) {
            atomicAdd(&pooled[g * 128 + t], acc);
            if (t == 0) atomicAdd(&gcnt[g], (float)run);
            acc = 0.f; run = 0; g = bg;
        }
        acc += __half2float(h[(size_t)n * 128 + t]);
        run++;
    }
    atomicAdd(&pooled[g * 128 + t], acc);
    if (t == 0) atomicAdd(&gcnt[g], (float)run);
}

// ---- FFN: out[g] = relu(pooled_mean @ Wf1 + bf1) @ Wf2 + bf2 ---------------
__global__ __launch_bounds__(128) void k_ffn(const float* __restrict__ pooled,
                                             const float* __restrict__ gcnt,
                                             const float* __restrict__ Wf1,
                                             const float* __restrict__ bf1,
                                             const float* __restrict__ Wf2,
                                             const float* __restrict__ bf2,
                                             float* __restrict__ out, int C) {
    __shared__ float pl[128];
    __shared__ float hid[128];
    int g = blockIdx.x;
    int t = threadIdx.x;
    float invc = 1.0f / fmaxf(gcnt[g], 1.0f);
    pl[t] = pooled[g * 128 + t] * invc;
    __syncthreads();
    float s = bf1[t];
    for (int k = 0; k < 128; ++k) s += pl[k] * Wf1[k * 128 + t];
    hid[t] = fmaxf(s, 0.f);
    __syncthreads();
    if (t < C) {
        float o = bf2[t];
        for (int f = 0; f < 128; ++f) o += hid[f] * Wf2[f * C + t];
        out[g * C + t] = o;
    }
}

extern "C" void kernel_launch(void* const* d_in, const int* in_sizes, int n_in,
                              void* d_out, int out_size, void* d_ws, size_t ws_size,
                              hipStream_t stream) {
    const float* x   = (const float*)d_in[0];
    const int*   ei  = (const int*)d_in[1];
    const int*   bat = (const int*)d_in[2];
    const float* W1  = (const float*)d_in[3];
    const float* b1  = (const float*)d_in[4];
    const float* W2  = (const float*)d_in[5];
    const float* b2  = (const float*)d_in[6];
    const float* W3  = (const float*)d_in[7];
    const float* b3  = (const float*)d_in[8];
    const float* Wf1 = (const float*)d_in[9];
    const float* bf1 = (const float*)d_in[10];
    const float* Wf2 = (const float*)d_in[11];
    const float* bf2 = (const float*)d_in[12];
    float* out = (float*)d_out;

    int N = in_sizes[2];
    int E = in_sizes[1] / 2;
    int C = in_sizes[12];
    const int* row  = ei;
    const int* colv = ei + E;

    int nbuck = (N + 255) / 256;
    int Npad  = nbuck * 256;

    auto align256 = [](char* p) {
        return (char*)(((uintptr_t)p + 255) & ~(uintptr_t)255);
    };
    char* w = (char*)d_ws;
    __half* bufX = (__half*)w; w += (size_t)N * 128 * 2; w = align256(w);
    __half* bufY = (__half*)w; w += (size_t)N * 128 * 2; w = align256(w);
    int* ell     = (int*)w;   w += (size_t)Npad * MAXDEG * 4; w = align256(w);
    int* recs    = (int*)w;   w += (size_t)nbuck * BUCKCAP * 4; w = align256(w);
    int* cnt     = (int*)w;   w += (size_t)Npad * 4;    w = align256(w);
    float* dinv  = (float*)w; w += (size_t)N * 4;       w = align256(w);
    int* gcur    = (int*)w;   w += NBUCKMAX * 4;        w = align256(w);
    __half* Wt1  = (__half*)w; w += 128 * 128 * 2;      w = align256(w);
    __half* Wt2  = (__half*)w; w += 128 * 128 * 2;      w = align256(w);
    __half* Wt3  = (__half*)w; w += 128 * 128 * 2;      w = align256(w);
    float* pooled= (float*)w;  w += 128 * 128 * 4;      w = align256(w);
    float* gcnt  = (float*)w;  w += 128 * 4;

    int nnode8 = (N + 7) / 8;
    int nlayer = (N + 63) / 64;

    k_cvtw  <<<64, 256, 0, stream>>>(W1, W2, W3, Wt1, Wt2, Wt3, pooled, gcnt, gcur);
    k_bucket<<<256, 256, 0, stream>>>(row, colv, E, nbuck, gcur, recs);
    k_build <<<nbuck, 256, 0, stream>>>(recs, gcur, ell, cnt, N);
    k_prep  <<<nnode8, 256, 0, stream>>>((const float4*)x, cnt, dinv,
                                         (float2*)bufX, N);

    // layer 1: bufX -> bufY (scaled)
    k_layer_f<<<nlayer, 512, 0, stream>>>((const float2*)bufX, ell, cnt,
                                          Wt1, b1, dinv, bufY, N, 1);
    // layer 2: bufY -> bufX (scaled)
    k_layer_f<<<nlayer, 512, 0, stream>>>((const float2*)bufY, ell, cnt,
                                          Wt2, b2, dinv, bufX, N, 1);
    // layer 3: bufX -> bufY (unscaled, for pooling)
    k_layer_f<<<nlayer, 512, 0, stream>>>((const float2*)bufX, ell, cnt,
                                          Wt3, b3, dinv, bufY, N, 0);

    k_pool<<<(N + 127) / 128, 128, 0, stream>>>(bufY, bat, pooled, gcnt, N);
    k_ffn <<<128, 128, 0, stream>>>(pooled, gcnt, Wf1, bf1, Wf2, bf2, out, C);
}

// Round 11
// 343.303 us; speedup vs baseline: 1.0249x; 1.0151x over previous
//
#include <hip/hip_runtime.h>
#include <hip/hip_fp16.h>

// ---------------------------------------------------------------------------
// GCN 3-layer forward (split pipeline, r8 structure).
//   g_l = dinv * h_l stored fp16 [N][128].  agg[dst] = sum_src g[src] + g[dst]
//   h_{l+1} = relu( dinv[dst]*(agg @ W) + b ); layers 1,2 store dinv*h.
// Adjacency: two-pass binned ELL build.
// GEMM: MFMA 32x32x16, Wt read directly from global (L1-resident, no LDS).
// Layer 3: GEMM fused with mean-pool (shfl reduce + LDS partials + atomics),
// skips the 25.6MB h write and the separate pool pass.
// ---------------------------------------------------------------------------

#define MAXDEG 64
#define NBUCKMAX 512
#define STAGE 32
#define BUCKCAP 8192

typedef _Float16 f16x8 __attribute__((ext_vector_type(8)));
typedef float f32x16 __attribute__((ext_vector_type(16)));

// ---- weights fp32->fp16 TRANSPOSED (Wt[f][k] = W[k][f]) + zero-inits -------
__global__ void k_cvtw(const float* __restrict__ W1, const float* __restrict__ W2,
                       const float* __restrict__ W3, __half* __restrict__ o1,
                       __half* __restrict__ o2, __half* __restrict__ o3,
                       float* __restrict__ pooled, float* __restrict__ gcnt,
                       int* __restrict__ gcur) {
    int i = blockIdx.x * blockDim.x + threadIdx.x;   // 16384, i = f*128+k
    int src = ((i & 127) << 7) + (i >> 7);           // W[k][f]
    o1[i] = __float2half_rn(W1[src]);
    o2[i] = __float2half_rn(W2[src]);
    o3[i] = __float2half_rn(W3[src]);
    pooled[i] = 0.f;
    if (i < 128) gcnt[i] = 0.f;
    if (i < NBUCKMAX) gcur[i] = 0;
}

// ---- pass A: bucket edges into per-bucket record regions -------------------
__global__ __launch_bounds__(256) void k_bucket(const int* __restrict__ row,
                                                const int* __restrict__ col,
                                                int E, int nbuck,
                                                int* __restrict__ gcur,
                                                int* __restrict__ recs) {
    __shared__ int stage[NBUCKMAX][STAGE];   // 64 KB
    __shared__ int scur[NBUCKMAX];
    int t = threadIdx.x;
    for (int i = t; i < NBUCKMAX; i += 256) scur[i] = 0;
    __syncthreads();

    int nblk = gridDim.x;
    int chunk = (((E + nblk - 1) / nblk) + 255) & ~255;
    int e0 = blockIdx.x * chunk;
    int e1 = e0 + chunk; if (e1 > E) e1 = E;

    for (int base = e0; base < e1; base += 256) {
        int e = base + t;
        if (e < e1) {
            int s = row[e], d = col[e];
            int b = d >> 8;
            int rec = (s << 8) | (d & 255);
            int slot = atomicAdd(&scur[b], 1);
            if (slot < STAGE) {
                stage[b][slot] = rec;
            } else {  // rare overflow: direct global
                int gp = atomicAdd(&gcur[b], 1);
                if (gp < BUCKCAP) recs[(size_t)b * BUCKCAP + gp] = rec;
            }
        }
        __syncthreads();
        for (int b = t; b < nbuck; b += 256) {
            int c = scur[b];
            if (c >= 24) {
                int n = c < STAGE ? c : STAGE;
                int gp = atomicAdd(&gcur[b], n);
                int* rg = recs + (size_t)b * BUCKCAP + gp;
                for (int k = 0; k < n; ++k) rg[k] = stage[b][k];
                scur[b] = 0;
            }
        }
        __syncthreads();
    }
    for (int b = t; b < nbuck; b += 256) {
        int c = scur[b];
        if (c > 0) {
            int n = c < STAGE ? c : STAGE;
            int gp = atomicAdd(&gcur[b], n);
            int* rg = recs + (size_t)b * BUCKCAP + gp;
            for (int k = 0; k < n; ++k) rg[k] = stage[b][k];
        }
    }
}

// ---- pass B: one block per bucket; build ELL slice (L2-resident) + cnt -----
__global__ __launch_bounds__(256) void k_build(const int* __restrict__ recs,
                                               const int* __restrict__ gcur,
                                               int* __restrict__ ell,
                                               int* __restrict__ cnt, int N) {
    __shared__ int lcnt[256];
    int b = blockIdx.x;
    int t = threadIdx.x;
    lcnt[t] = 0;
    __syncthreads();
    int n = gcur[b]; if (n > BUCKCAP) n = BUCKCAP;
    const int* rp = recs + (size_t)b * BUCKCAP;
    int base = b << 8;
    for (int i = t; i < n; i += 256) {
        int rec = rp[i];
        int dl = rec & 255;
        int s = rec >> 8;
        int r = atomicAdd(&lcnt[dl], 1);
        if (r < MAXDEG) ell[(size_t)(base + dl) * MAXDEG + r] = s;
    }
    __syncthreads();
    int node = base + t;
    if (node < N) cnt[node] = lcnt[t];
}

// ---- fused dinv + convert x -> g0 = dinv*x (fp16 [N][32] float2) -----------
__global__ __launch_bounds__(256) void k_prep(const float4* __restrict__ x,
                                              const int* __restrict__ cnt,
                                              float* __restrict__ dinv,
                                              float2* __restrict__ g0, int N) {
    int t = threadIdx.x;
    int slot = t >> 5, lane = t & 31;
    int node = blockIdx.x * 8 + slot;
    if (node >= N) return;
    float sc = rsqrtf((float)cnt[node] + 1.0f);
    if (lane == 0) dinv[node] = sc;
    float4 v = x[(size_t)node * 32 + lane];
    float2 o;
    ((__half2*)&o)[0] = __float22half2_rn(make_float2(v.x * sc, v.y * sc));
    ((__half2*)&o)[1] = __float22half2_rn(make_float2(v.z * sc, v.w * sc));
    g0[(size_t)node * 32 + lane] = o;
}

// ---- aggregate: half-wave (32 lanes) per node, 8B/lane, 8 rows in flight ---
__global__ __launch_bounds__(256) void k_agg(const float2* __restrict__ gin,
                                             const int* __restrict__ ell,
                                             const int* __restrict__ cnt,
                                             float2* __restrict__ gout, int N) {
    int t = threadIdx.x;
    int slot = t >> 5;        // 0..7
    int lane = t & 31;
    int node = blockIdx.x * 8 + slot;
    if (node >= N) return;

    float2 s = gin[(size_t)node * 32 + lane];
    float2 a0 = __half22float2(((const __half2*)&s)[0]);   // self loop
    float2 a1 = __half22float2(((const __half2*)&s)[1]);

    int deg = cnt[node]; if (deg > MAXDEG) deg = MAXDEG;
    const int* rowp = ell + (size_t)node * MAXDEG;
    int j = 0;
    for (; j + 7 < deg; j += 8) {
        int4 sa = *(const int4*)(rowp + j);
        int4 sb = *(const int4*)(rowp + j + 4);
        float2 v0 = gin[(size_t)sa.x * 32 + lane];
        float2 v1 = gin[(size_t)sa.y * 32 + lane];
        float2 v2 = gin[(size_t)sa.z * 32 + lane];
        float2 v3 = gin[(size_t)sa.w * 32 + lane];
        float2 v4 = gin[(size_t)sb.x * 32 + lane];
        float2 v5 = gin[(size_t)sb.y * 32 + lane];
        float2 v6 = gin[(size_t)sb.z * 32 + lane];
        float2 v7 = gin[(size_t)sb.w * 32 + lane];
        float2 f;
        f = __half22float2(((const __half2*)&v0)[0]); a0.x += f.x; a0.y += f.y;
        f = __half22float2(((const __half2*)&v0)[1]); a1.x += f.x; a1.y += f.y;
        f = __half22float2(((const __half2*)&v1)[0]); a0.x += f.x; a0.y += f.y;
        f = __half22float2(((const __half2*)&v1)[1]); a1.x += f.x; a1.y += f.y;
        f = __half22float2(((const __half2*)&v2)[0]); a0.x += f.x; a0.y += f.y;
        f = __half22float2(((const __half2*)&v2)[1]); a1.x += f.x; a1.y += f.y;
        f = __half22float2(((const __half2*)&v3)[0]); a0.x += f.x; a0.y += f.y;
        f = __half22float2(((const __half2*)&v3)[1]); a1.x += f.x; a1.y += f.y;
        f = __half22float2(((const __half2*)&v4)[0]); a0.x += f.x; a0.y += f.y;
        f = __half22float2(((const __half2*)&v4)[1]); a1.x += f.x; a1.y += f.y;
        f = __half22float2(((const __half2*)&v5)[0]); a0.x += f.x; a0.y += f.y;
        f = __half22float2(((const __half2*)&v5)[1]); a1.x += f.x; a1.y += f.y;
        f = __half22float2(((const __half2*)&v6)[0]); a0.x += f.x; a0.y += f.y;
        f = __half22float2(((const __half2*)&v6)[1]); a1.x += f.x; a1.y += f.y;
        f = __half22float2(((const __half2*)&v7)[0]); a0.x += f.x; a0.y += f.y;
        f = __half22float2(((const __half2*)&v7)[1]); a1.x += f.x; a1.y += f.y;
    }
    for (; j + 3 < deg; j += 4) {
        int4 s4 = *(const int4*)(rowp + j);
        float2 v0 = gin[(size_t)s4.x * 32 + lane];
        float2 v1 = gin[(size_t)s4.y * 32 + lane];
        float2 v2 = gin[(size_t)s4.z * 32 + lane];
        float2 v3 = gin[(size_t)s4.w * 32 + lane];
        float2 f;
        f = __half22float2(((const __half2*)&v0)[0]); a0.x += f.x; a0.y += f.y;
        f = __half22float2(((const __half2*)&v0)[1]); a1.x += f.x; a1.y += f.y;
        f = __half22float2(((const __half2*)&v1)[0]); a0.x += f.x; a0.y += f.y;
        f = __half22float2(((const __half2*)&v1)[1]); a1.x += f.x; a1.y += f.y;
        f = __half22float2(((const __half2*)&v2)[0]); a0.x += f.x; a0.y += f.y;
        f = __half22float2(((const __half2*)&v2)[1]); a1.x += f.x; a1.y += f.y;
        f = __half22float2(((const __half2*)&v3)[0]); a0.x += f.x; a0.y += f.y;
        f = __half22float2(((const __half2*)&v3)[1]); a1.x += f.x; a1.y += f.y;
    }
    for (; j < deg; ++j) {
        int s0 = rowp[j];
        float2 v0 = gin[(size_t)s0 * 32 + lane];
        float2 f;
        f = __half22float2(((const __half2*)&v0)[0]); a0.x += f.x; a0.y += f.y;
        f = __half22float2(((const __half2*)&v0)[1]); a1.x += f.x; a1.y += f.y;
    }
    float2 o;
    ((__half2*)&o)[0] = __float22half2_rn(a0);
    ((__half2*)&o)[1] = __float22half2_rn(a1);
    gout[(size_t)node * 32 + lane] = o;
}

// ---- MFMA dense (layers 1,2): Wt direct from global, no LDS, no barrier ----
__global__ __launch_bounds__(256) void k_gemm_mfma(
    const __half* __restrict__ in,   // [N][128] fp16
    const __half* __restrict__ Wt,   // [128 f][128 k] fp16 (= W^T), L1-hot
    const float* __restrict__ bias,
    const float* __restrict__ dinv,
    __half* __restrict__ outp,       // [N][128] fp16
    int N)
{
    int t = threadIdx.x;
    int wave = t >> 6, lane = t & 63;
    int ln31 = lane & 31;
    int khalf = lane >> 5;                     // 0/1
    int node = blockIdx.x * 128 + wave * 32 + ln31;
    bool valid = node < N;
    size_t nrow = (size_t)(valid ? node : 0) * 128;

    f16x8 bfrag[8];
    const f16x8* inrow = (const f16x8*)(in + nrow);
#pragma unroll
    for (int kc = 0; kc < 8; ++kc) bfrag[kc] = inrow[kc * 2 + khalf];

    float scn = dinv[valid ? node : 0];
    const float4* Wg4 = (const float4*)Wt;

#pragma unroll
    for (int ft = 0; ft < 4; ++ft) {
        f32x16 acc = {0.f, 0.f, 0.f, 0.f, 0.f, 0.f, 0.f, 0.f,
                      0.f, 0.f, 0.f, 0.f, 0.f, 0.f, 0.f, 0.f};
#pragma unroll
        for (int kc = 0; kc < 8; ++kc) {
            int aidx = (ft * 32 + ln31) * 16 + kc * 2 + khalf;
            f16x8 afrag = *(const f16x8*)&Wg4[aidx];
            acc = __builtin_amdgcn_mfma_f32_32x32x16_f16(afrag, bfrag[kc], acc, 0, 0, 0);
        }
        if (valid) {
#pragma unroll
            for (int q = 0; q < 4; ++q) {
                int f = ft * 32 + q * 8 + khalf * 4;
                float4 bb = *(const float4*)&bias[f];
                float o0 = fmaxf(acc[q * 4 + 0] * scn + bb.x, 0.f) * scn;
                float o1 = fmaxf(acc[q * 4 + 1] * scn + bb.y, 0.f) * scn;
                float o2 = fmaxf(acc[q * 4 + 2] * scn + bb.z, 0.f) * scn;
                float o3 = fmaxf(acc[q * 4 + 3] * scn + bb.w, 0.f) * scn;
                float2 st;
                ((__half2*)&st)[0] = __float22half2_rn(make_float2(o0, o1));
                ((__half2*)&st)[1] = __float22half2_rn(make_float2(o2, o3));
                *(float2*)&outp[nrow + f] = st;
            }
        }
    }
}

// ---- layer 3: MFMA + fused mean-pool (no h write) ---------------------------
__global__ __launch_bounds__(256) void k_gemm_pool(
    const __half* __restrict__ in,   // [N][128] fp16 (agg output)
    const __half* __restrict__ Wt,
    const float* __restrict__ bias,
    const float* __restrict__ dinv,
    const int* __restrict__ batch,   // sorted
    float* __restrict__ pooled,      // [128][128], pre-zeroed
    float* __restrict__ gcnt,        // [128], pre-zeroed
    int N)
{
    __shared__ float pp[8][128];     // per-block graph partials (4 KB)
    __shared__ float pc[8];
    int t = threadIdx.x;
    int nb = blockIdx.x * 128;
    int lastn = nb + 127; if (lastn > N - 1) lastn = N - 1;
    int gs = batch[nb];
    int ge = batch[lastn];
    int ng = ge - gs + 1;

    for (int i = t; i < 8 * 128; i += 256) ((float*)pp)[i] = 0.f;
    if (t < 8) pc[t] = 0.f;
    __syncthreads();

    int wave = t >> 6, lane = t & 63;
    int ln31 = lane & 31;
    int khalf = lane >> 5;
    int node = nb + wave * 32 + ln31;
    bool valid = node < N;
    size_t nrow = (size_t)(valid ? node : 0) * 128;
    int g_lane = valid ? batch[node] : -1;

    f16x8 bfrag[8];
    const f16x8* inrow = (const f16x8*)(in + nrow);
#pragma unroll
    for (int kc = 0; kc < 8; ++kc) bfrag[kc] = inrow[kc * 2 + khalf];

    float scn = dinv[valid ? node : 0];
    const float4* Wg4 = (const float4*)Wt;

    // node count per graph (once, khalf==0 half only)
    for (int gg = 0; gg < ng; ++gg) {
        float cv = (khalf == 0 && g_lane == gs + gg) ? 1.f : 0.f;
#pragma unroll
        for (int m = 1; m <= 16; m <<= 1) cv += __shfl_xor(cv, m);
        if (lane == 0 && cv != 0.f) atomicAdd(&pc[gg < 8 ? gg : 7], cv);
    }

#pragma unroll
    for (int ft = 0; ft < 4; ++ft) {
        f32x16 acc = {0.f, 0.f, 0.f, 0.f, 0.f, 0.f, 0.f, 0.f,
                      0.f, 0.f, 0.f, 0.f, 0.f, 0.f, 0.f, 0.f};
#pragma unroll
        for (int kc = 0; kc < 8; ++kc) {
            int aidx = (ft * 32 + ln31) * 16 + kc * 2 + khalf;
            f16x8 afrag = *(const f16x8*)&Wg4[aidx];
            acc = __builtin_amdgcn_mfma_f32_32x32x16_f16(afrag, bfrag[kc], acc, 0, 0, 0);
        }
#pragma unroll
        for (int q = 0; q < 4; ++q) {
            int f = ft * 32 + q * 8 + khalf * 4;
            float4 bb = *(const float4*)&bias[f];
            float h0 = fmaxf(acc[q * 4 + 0] * scn + bb.x, 0.f);
            float h1 = fmaxf(acc[q * 4 + 1] * scn + bb.y, 0.f);
            float h2 = fmaxf(acc[q * 4 + 2] * scn + bb.z, 0.f);
            float h3 = fmaxf(acc[q * 4 + 3] * scn + bb.w, 0.f);
            for (int gg = 0; gg < ng; ++gg) {
                int g = gs + gg;
                bool m = (g_lane == g);
                float v0 = m ? h0 : 0.f, v1 = m ? h1 : 0.f;
                float v2 = m ? h2 : 0.f, v3 = m ? h3 : 0.f;
#pragma unroll
                for (int mm = 1; mm <= 16; mm <<= 1) {
                    v0 += __shfl_xor(v0, mm);
                    v1 += __shfl_xor(v1, mm);
                    v2 += __shfl_xor(v2, mm);
                    v3 += __shfl_xor(v3, mm);
                }
                if (ln31 == 0) {
                    if (gg < 8) {
                        if (v0 != 0.f) atomicAdd(&pp[gg][f + 0], v0);
                        if (v1 != 0.f) atomicAdd(&pp[gg][f + 1], v1);
                        if (v2 != 0.f) atomicAdd(&pp[gg][f + 2], v2);
                        if (v3 != 0.f) atomicAdd(&pp[gg][f + 3], v3);
                    } else {  // pathological many-graphs fallback
                        if (v0 != 0.f) atomicAdd(&pooled[g * 128 + f + 0], v0);
                        if (v1 != 0.f) atomicAdd(&pooled[g * 128 + f + 1], v1);
                        if (v2 != 0.f) atomicAdd(&pooled[g * 128 + f + 2], v2);
                        if (v3 != 0.f) atomicAdd(&pooled[g * 128 + f + 3], v3);
                    }
                }
            }
        }
    }
    __syncthreads();
    int ngc = ng < 8 ? ng : 8;
    if (t < 128) {
        for (int gg = 0; gg < ngc; ++gg) {
            float v = pp[gg][t];
            if (v != 0.f) atomicAdd(&pooled[(gs + gg) * 128 + t], v);
        }
    }
    if (t == 0) {
        for (int gg = 0; gg < ngc; ++gg)
            if (pc[gg] != 0.f) atomicAdd(&gcnt[gs + gg], pc[gg]);
    }
}

// ---- FFN: out[g] = relu(pooled_mean @ Wf1 + bf1) @ Wf2 + bf2 ---------------
__global__ __launch_bounds__(128) void k_ffn(const float* __restrict__ pooled,
                                             const float* __restrict__ gcnt,
                                             const float* __restrict__ Wf1,
                                             const float* __restrict__ bf1,
                                             const float* __restrict__ Wf2,
                                             const float* __restrict__ bf2,
                                             float* __restrict__ out, int C) {
    __shared__ float pl[128];
    __shared__ float hid[128];
    int g = blockIdx.x;
    int t = threadIdx.x;
    float invc = 1.0f / fmaxf(gcnt[g], 1.0f);
    pl[t] = pooled[g * 128 + t] * invc;
    __syncthreads();
    float s = bf1[t];
    for (int k = 0; k < 128; ++k) s += pl[k] * Wf1[k * 128 + t];
    hid[t] = fmaxf(s, 0.f);
    __syncthreads();
    if (t < C) {
        float o = bf2[t];
        for (int f = 0; f < 128; ++f) o += hid[f] * Wf2[f * C + t];
        out[g * C + t] = o;
    }
}

extern "C" void kernel_launch(void* const* d_in, const int* in_sizes, int n_in,
                              void* d_out, int out_size, void* d_ws, size_t ws_size,
                              hipStream_t stream) {
    const float* x   = (const float*)d_in[0];
    const int*   ei  = (const int*)d_in[1];
    const int*   bat = (const int*)d_in[2];
    const float* W1  = (const float*)d_in[3];
    const float* b1  = (const float*)d_in[4];
    const float* W2  = (const float*)d_in[5];
    const float* b2  = (const float*)d_in[6];
    const float* W3  = (const float*)d_in[7];
    const float* b3  = (const float*)d_in[8];
    const float* Wf1 = (const float*)d_in[9];
    const float* bf1 = (const float*)d_in[10];
    const float* Wf2 = (const float*)d_in[11];
    const float* bf2 = (const float*)d_in[12];
    float* out = (float*)d_out;

    int N = in_sizes[2];
    int E = in_sizes[1] / 2;
    int C = in_sizes[12];
    const int* row  = ei;
    const int* colv = ei + E;

    int nbuck = (N + 255) / 256;
    int Npad  = nbuck * 256;

    auto align256 = [](char* p) {
        return (char*)(((uintptr_t)p + 255) & ~(uintptr_t)255);
    };
    char* w = (char*)d_ws;
    __half* bufX = (__half*)w; w += (size_t)N * 128 * 2; w = align256(w);
    __half* bufY = (__half*)w; w += (size_t)N * 128 * 2; w = align256(w);
    __half* bufZ = (__half*)w; w += (size_t)N * 128 * 2; w = align256(w);
    int* ell     = (int*)w;   w += (size_t)Npad * MAXDEG * 4; w = align256(w);
    int* recs    = (int*)w;   w += (size_t)nbuck * BUCKCAP * 4; w = align256(w);
    int* cnt     = (int*)w;   w += (size_t)Npad * 4;    w = align256(w);
    float* dinv  = (float*)w; w += (size_t)N * 4;       w = align256(w);
    int* gcur    = (int*)w;   w += NBUCKMAX * 4;        w = align256(w);
    __half* Wt1  = (__half*)w; w += 128 * 128 * 2;      w = align256(w);
    __half* Wt2  = (__half*)w; w += 128 * 128 * 2;      w = align256(w);
    __half* Wt3  = (__half*)w; w += 128 * 128 * 2;      w = align256(w);
    float* pooled= (float*)w;  w += 128 * 128 * 4;      w = align256(w);
    float* gcnt  = (float*)w;  w += 128 * 4;

    int nnode8 = (N + 7) / 8;
    int ngemm  = (N + 127) / 128;

    k_cvtw  <<<64, 256, 0, stream>>>(W1, W2, W3, Wt1, Wt2, Wt3, pooled, gcnt, gcur);
    k_bucket<<<256, 256, 0, stream>>>(row, colv, E, nbuck, gcur, recs);
    k_build <<<nbuck, 256, 0, stream>>>(recs, gcur, ell, cnt, N);
    k_prep  <<<nnode8, 256, 0, stream>>>((const float4*)x, cnt, dinv,
                                         (float2*)bufX, N);

    // layer 1: bufX -> agg bufZ -> gemm bufY (scaled)
    k_agg <<<nnode8, 256, 0, stream>>>((const float2*)bufX, ell, cnt,
                                       (float2*)bufZ, N);
    k_gemm_mfma<<<ngemm, 256, 0, stream>>>(bufZ, Wt1, b1, dinv, bufY, N);
    // layer 2: bufY -> agg bufZ -> gemm bufX (scaled)
    k_agg <<<nnode8, 256, 0, stream>>>((const float2*)bufY, ell, cnt,
                                       (float2*)bufZ, N);
    k_gemm_mfma<<<ngemm, 256, 0, stream>>>(bufZ, Wt2, b2, dinv, bufX, N);
    // layer 3: bufX -> agg bufZ -> gemm+pool (no h write)
    k_agg <<<nnode8, 256, 0, stream>>>((const float2*)bufX, ell, cnt,
                                       (float2*)bufZ, N);
    k_gemm_pool<<<ngemm, 256, 0, stream>>>(bufZ, Wt3, b3, dinv, bat,
                                           pooled, gcnt, N);

    k_ffn <<<128, 128, 0, stream>>>(pooled, gcnt, Wf1, bf1, Wf2, bf2, out, C);
}